// Round 22
// baseline (133.905 us; speedup 1.0000x reference)
//
#include <hip/hip_runtime.h>

typedef __bf16 bf16;
typedef bf16 bf16x8 __attribute__((ext_vector_type(8)));
typedef bf16 bf16x4 __attribute__((ext_vector_type(4)));
typedef float f32x4 __attribute__((ext_vector_type(4)));
typedef float f32x16 __attribute__((ext_vector_type(16)));
typedef unsigned int u32;

#define DEV_INLINE __device__ __forceinline__

DEV_INLINE f32x4 mfma16(bf16x8 a, bf16x8 b, f32x4 c) {
    return __builtin_amdgcn_mfma_f32_16x16x32_bf16(a, b, c, 0, 0, 0);
}
DEV_INLINE f32x16 mfma32(bf16x8 a, bf16x8 b, f32x16 c) {
    return __builtin_amdgcn_mfma_f32_32x32x16_bf16(a, b, c, 0, 0, 0);
}

#define GLD16(gp, lp) __builtin_amdgcn_global_load_lds( \
    (const __attribute__((address_space(1))) void*)(gp), \
    (__attribute__((address_space(3))) void*)(lp), 16, 0, 0)

// ---------------- transpose cast: in f32 [K][N] -> out bf16 [N][K] ----------------
__global__ void transpose_cast_kernel(const float* __restrict__ in, bf16* __restrict__ out,
                                      int K, int N) {
    int idx = blockIdx.x * blockDim.x + threadIdx.x;
    if (idx < K * N) {
        int n = idx / K, k = idx - n * K;
        out[idx] = (bf16)in[k * N + n];
    }
}

// ---------------- kv GEMM: x f32 [8192x512] x W_kv^T -> K bf16 natural, V bf16 head-transposed
// A staged directly from f32 (cast fused). V t-index PERMUTED (swap bits 2,3
// within each 16-run) so the attention PV A-fragment is one contiguous 16B chunk.
__launch_bounds__(256, 2)
__global__ void gemm_kv_kernel(const float* __restrict__ A,  // x f32 [8192][512]
                               const bf16* __restrict__ Bt,  // W_kv^T bf16 [1024][512]
                               bf16* __restrict__ Kout,      // [8][1024][512]
                               bf16* __restrict__ Vt)        // [8][8][64][1024] (t-permuted)
{
    __shared__ bf16 As[128][32];
    __shared__ bf16 Bs[128][32];
    const int bm = blockIdx.x, bn = blockIdx.y;
    const int tid = threadIdx.x;
    const int lane = tid & 63, w = tid >> 6;
    const int wm = (w >> 1) * 64, wn = (w & 1) * 64;
    const int lr = lane & 15, kg = lane >> 4;

    const f32x4 fz = {0.f, 0.f, 0.f, 0.f};
    f32x4 acc[4][4];
    for (int i = 0; i < 4; ++i)
        for (int j = 0; j < 4; ++j) acc[i][j] = fz;

    const int srow = tid >> 2, sc4 = tid & 3;

    for (int k0 = 0; k0 < 512; k0 += 32) {
        __syncthreads();
        for (int rr = 0; rr < 2; ++rr) {
            int row = srow + rr * 64;
            const float* ap = A + (size_t)(bm * 128 + row) * 512 + k0 + (sc4 << 3);
            f32x4 a0 = *reinterpret_cast<const f32x4*>(ap);
            f32x4 a1 = *reinterpret_cast<const f32x4*>(ap + 4);
            bf16x8 av;
            for (int j = 0; j < 4; ++j) { av[j] = (bf16)a0[j]; av[4 + j] = (bf16)a1[j]; }
            *reinterpret_cast<bf16x8*>(&As[row][(sc4 ^ (row & 3)) << 3]) = av;
            *reinterpret_cast<bf16x8*>(&Bs[row][(sc4 ^ (row & 3)) << 3]) =
                *reinterpret_cast<const bf16x8*>(Bt + (size_t)(bn * 128 + row) * 512 + k0 + (sc4 << 3));
        }
        __syncthreads();
        bf16x8 af[4], bfr[4];
        for (int mi = 0; mi < 4; ++mi) {
            int row = wm + mi * 16 + lr;
            af[mi] = *reinterpret_cast<const bf16x8*>(&As[row][(kg ^ (row & 3)) << 3]);
        }
        for (int ni = 0; ni < 4; ++ni) {
            int row = wn + ni * 16 + lr;
            bfr[ni] = *reinterpret_cast<const bf16x8*>(&Bs[row][(kg ^ (row & 3)) << 3]);
        }
        for (int mi = 0; mi < 4; ++mi)
            for (int ni = 0; ni < 4; ++ni)
                acc[mi][ni] = mfma16(af[mi], bfr[ni], acc[mi][ni]);
    }

    for (int mi = 0; mi < 4; ++mi) {
        int mbase = bm * 128 + wm + mi * 16 + kg * 4;  // C/D: row=(lane>>4)*4+reg
        for (int ni = 0; ni < 4; ++ni) {
            int col = bn * 128 + wn + ni * 16 + lr;    // C/D: col=lane&15
            if (col < 512) {
                for (int r = 0; r < 4; ++r)
                    Kout[(size_t)(mbase + r) * 512 + col] = (bf16)acc[mi][ni][r];
            } else {
                int c = col - 512, h = c >> 6, d = c & 63;
                int b = mbase >> 10, t = mbase & 1023;  // 4 rows share batch (4-aligned)
                int tp = (t & ~12) | ((t & 4) << 1) | ((t & 8) >> 1);  // swap bits 2,3
                bf16x4 pk;
                for (int r = 0; r < 4; ++r) pk[r] = (bf16)acc[mi][ni][r];
                *reinterpret_cast<bf16x4*>(Vt + (size_t)((b * 8 + h) * 64 + d) * 1024 + tp) = pk;
            }
        }
    }
}

// ---------------- proj GEMM: Y[8192x512] x Wp^T[512][512] -> f32 out ----------------
__launch_bounds__(256, 2)
__global__ void gemm_proj_kernel(const bf16* __restrict__ A,   // Y bf16 [8192][512]
                                 const bf16* __restrict__ Bt,  // W_proj^T bf16 [512][512]
                                 float* __restrict__ out)      // [8192][512]
{
    __shared__ bf16 As[128][32];
    __shared__ bf16 Bs[128][32];
    const int bm = blockIdx.x, bn = blockIdx.y;
    const int tid = threadIdx.x;
    const int lane = tid & 63, w = tid >> 6;
    const int wm = (w >> 1) * 64, wn = (w & 1) * 64;
    const int lr = lane & 15, kg = lane >> 4;

    const f32x4 fz = {0.f, 0.f, 0.f, 0.f};
    f32x4 acc[4][4];
    for (int i = 0; i < 4; ++i)
        for (int j = 0; j < 4; ++j) acc[i][j] = fz;

    const int srow = tid >> 2, sc4 = tid & 3;

    for (int k0 = 0; k0 < 512; k0 += 32) {
        __syncthreads();
        for (int rr = 0; rr < 2; ++rr) {
            int row = srow + rr * 64;
            *reinterpret_cast<bf16x8*>(&As[row][(sc4 ^ (row & 3)) << 3]) =
                *reinterpret_cast<const bf16x8*>(A + (size_t)(bm * 128 + row) * 512 + k0 + (sc4 << 3));
            *reinterpret_cast<bf16x8*>(&Bs[row][(sc4 ^ (row & 3)) << 3]) =
                *reinterpret_cast<const bf16x8*>(Bt + (size_t)(bn * 128 + row) * 512 + k0 + (sc4 << 3));
        }
        __syncthreads();
        bf16x8 af[4], bfr[4];
        for (int mi = 0; mi < 4; ++mi) {
            int row = wm + mi * 16 + lr;
            af[mi] = *reinterpret_cast<const bf16x8*>(&As[row][(kg ^ (row & 3)) << 3]);
        }
        for (int ni = 0; ni < 4; ++ni) {
            int row = wn + ni * 16 + lr;
            bfr[ni] = *reinterpret_cast<const bf16x8*>(&Bs[row][(kg ^ (row & 3)) << 3]);
        }
        for (int mi = 0; mi < 4; ++mi)
            for (int ni = 0; ni < 4; ++ni)
                acc[mi][ni] = mfma16(af[mi], bfr[ni], acc[mi][ni]);
    }

    for (int mi = 0; mi < 4; ++mi) {
        int mbase = bm * 128 + wm + mi * 16 + kg * 4;
        for (int ni = 0; ni < 4; ++ni) {
            int col = bn * 128 + wn + ni * 16 + lr;
            for (int r = 0; r < 4; ++r)
                out[(size_t)(mbase + r) * 512 + col] = acc[mi][ni][r];
        }
    }
}

// ---------------- flash attention: r21 body, 4-way S-SPLIT ----------------
// 1024 blocks x 8 waves (4-way S-split x 4 qseg x 8 h x 8 b), 18 tiles of 64 s.
// Body identical to r21 (conflict-free [32x128] packed LDS, raw v_exp_f32,
// zero-C first MFMA). VGPR=64 at (512,2) -> HW can co-schedule 4 blocks/CU.
__launch_bounds__(512, 2)
__global__ void attn_kernel(const float* __restrict__ Qr,  // q f32 [8][1024][512]
                            const bf16* __restrict__ Kb,   // [8][1024][512]
                            const bf16* __restrict__ Vt,   // [8][8][64][1024] t-permuted
                            bf16* __restrict__ Op01,       // parts 0,1: [2][8192][512] bf16
                            bf16* __restrict__ Op23,       // parts 2,3: [2][8192][512] bf16
                            float* __restrict__ Lp)        // [4][8][8192] partial l
{
    __shared__ bf16 sK[2][32][128];
    __shared__ bf16 sV[2][32][128];

    const int raw = blockIdx.x;
    const int h = raw & 7;              // head on low bits -> per-XCD K/V locality
    const int shalf = (raw >> 3) & 3;   // S-quarter
    const int qseg = (raw >> 5) & 3;
    const int b = raw >> 7;
    const int tid = threadIdx.x, lane = tid & 63, w = tid >> 6;   // w in 0..7
    const int lq = lane & 31, hi = lane >> 5;
    const int qrow = b * 1024 + qseg * 256 + w * 32 + lq;
    const int sbase = shalf * 1152;     // 18 tiles of 64 s

    // Q B-fragments from f32 with fused scale (1/8 * log2e): col=q=lane&31
    const float QSC = 0.18033688011112306f;
    bf16x8 qf[4];
#pragma unroll
    for (int ds = 0; ds < 4; ++ds) {
        const float* qp = Qr + (size_t)qrow * 512 + h * 64 + ds * 16 + hi * 8;
        f32x4 q0 = *reinterpret_cast<const f32x4*>(qp);
        f32x4 q1 = *reinterpret_cast<const f32x4*>(qp + 4);
#pragma unroll
        for (int j = 0; j < 4; ++j) {
            qf[ds][j]     = (bf16)(q0[j] * QSC);
            qf[ds][4 + j] = (bf16)(q1[j] * QSC);
        }
    }

    const f32x16 Z16 = {0,0,0,0,0,0,0,0,0,0,0,0,0,0,0,0};
    f32x16 O0 = Z16, O1 = Z16, lv = Z16;

    // ---- read offsets: logical (row=lq, chunk c) -> packed layout ----
    const bf16* Kf = &sK[0][0][0];
    const bf16* Vf = &sV[0][0][0];
    int koffE[4];
#pragma unroll
    for (int ds = 0; ds < 4; ++ds) {
        int c = ds * 2 + hi;
        int r = lq >> 1;
        int cc = ((lq & 1) << 3) | c;
        koffE[ds] = r * 128 + ((cc ^ r) << 3);
    }

    // ---- staging geometry (packed [32][128], 16-wide XOR) ----
    const int rl = w * 4 + (lane >> 4);
    const int ccs = (lane & 15) ^ (rl & 15);
    const int srow2 = w * 8 + 2 * (lane >> 4) + (ccs >> 3);   // logical source row in tile
    const size_t koff = (size_t)srow2 * 512 + (ccs & 7) * 8;
    const size_t voff = (size_t)srow2 * 1024 + (ccs & 7) * 8;

    auto kv_base = [&](int t, const bf16*& kp, const bf16*& vp) {
        int gs = sbase + t * 64;         // global s offset, 0..4544
        int jj = gs >> 9, tin = gs & 511;
        if (jj < 7) {
            int m7 = 7 * b + jj;
            int src_b = ((m7 & 7) - (m7 >> 3)) & 7;
            kp = Kb + (size_t)(src_b * 1024 + tin) * 512 + h * 64;
            vp = Vt + (size_t)((src_b * 8 + h) * 64) * 1024 + tin;
        } else {
            int tpos = (jj - 7) * 512 + tin;
            kp = Kb + (size_t)(b * 1024 + tpos) * 512 + h * 64;
            vp = Vt + (size_t)((b * 8 + h) * 64) * 1024 + tpos;
        }
    };

    auto stage = [&](int buf, int t) {
        const bf16 *kp, *vp;
        kv_base(t, kp, vp);
        GLD16(kp + koff, &sK[buf][w * 4][0]);
        GLD16(vp + voff, &sV[buf][w * 4][0]);
    };

    // compute one 64-s tile (cb must be a literal at the call site)
    auto computeTile = [&](int cb) {
        const int kb = cb * 4096;
        f32x16 s0, s1;
        __builtin_amdgcn_s_setprio(1);
        {   // first k-slice consumes the persistent zero C (no 32x mov init)
            bf16x8 k0 = *reinterpret_cast<const bf16x8*>(Kf + kb + koffE[0]);
            bf16x8 k1 = *reinterpret_cast<const bf16x8*>(Kf + kb + 2048 + koffE[0]);
            s0 = mfma32(k0, qf[0], Z16);
            s1 = mfma32(k1, qf[0], Z16);
        }
#pragma unroll
        for (int ds = 1; ds < 4; ++ds) {
            bf16x8 k0 = *reinterpret_cast<const bf16x8*>(Kf + kb + koffE[ds]);
            bf16x8 k1 = *reinterpret_cast<const bf16x8*>(Kf + kb + 2048 + koffE[ds]);
            s0 = mfma32(k0, qf[ds], s0);
            s1 = mfma32(k1, qf[ds], s1);
        }
        __builtin_amdgcn_s_setprio(0);

        // softmax numerator: p = 2^s, raw v_exp_f32 (scale cancels in O/l)
#pragma unroll
        for (int i = 0; i < 16; ++i) {
            float p0 = __builtin_amdgcn_exp2f(s0[i]); s0[i] = p0;
            float p1 = __builtin_amdgcn_exp2f(s1[i]); s1[i] = p1;
            lv[i] += p0 + p1;
        }

        __builtin_amdgcn_s_setprio(1);
#pragma unroll
        for (int ssub = 0; ssub < 4; ++ssub) {
            bf16x8 pf;
#pragma unroll
            for (int i = 0; i < 8; ++i) {
                float pv = (ssub < 2) ? ((ssub & 1) ? s0[8 + i] : s0[i])
                                      : ((ssub & 1) ? s1[8 + i] : s1[i]);
                pf[i] = (bf16)pv;
            }
            bf16x8 a0 = *reinterpret_cast<const bf16x8*>(Vf + kb + koffE[ssub]);
            bf16x8 a1 = *reinterpret_cast<const bf16x8*>(Vf + kb + 2048 + koffE[ssub]);
            O0 = mfma32(a0, pf, O0);
            O1 = mfma32(a1, pf, O1);
        }
        __builtin_amdgcn_s_setprio(0);
    };

    stage(0, 0);   // prologue

    // 18 tiles of 64 s: each iteration computes tiles t (buf0) and t+1 (buf1)
    for (int t = 0; t < 18; t += 2) {
        __syncthreads();                    // drains vmcnt (stage writes) + barrier
        stage(1, t + 1);
        computeTile(0);
        __syncthreads();
        if (t + 2 < 18) stage(0, t + 2);
        computeTile(1);
    }

    // ---- epilogue: reduce partial l, store partial O^T (UNnormalized, bf16) + l ----
    float lrun = 0.f;
#pragma unroll
    for (int i = 0; i < 16; ++i) lrun += lv[i];
    lrun += __shfl_xor(lrun, 32);
    if (hi == 0) Lp[shalf * 65536 + h * 8192 + qrow] = lrun;

    bf16* Od = (shalf < 2 ? Op01 + (size_t)shalf * 4194304
                          : Op23 + (size_t)(shalf - 2) * 4194304);
#pragma unroll
    for (int dh = 0; dh < 2; ++dh) {
#pragma unroll
        for (int q4 = 0; q4 < 4; ++q4) {
            bf16x4 pk;
#pragma unroll
            for (int i = 0; i < 4; ++i)
                pk[i] = (bf16)(dh ? O1[q4 * 4 + i] : O0[q4 * 4 + i]);
            *reinterpret_cast<bf16x4*>(
                Od + (size_t)qrow * 512 + h * 64 + dh * 32 + q4 * 8 + hi * 4) = pk;
        }
    }
}

// ---------------- combine partials: Y = (O0+O1+O2+O3) / (l0+l1+l2+l3), bf16 ----------------
__global__ void combine_kernel(const bf16* __restrict__ Op01, const bf16* __restrict__ Op23,
                               const float* __restrict__ Lp, bf16* __restrict__ Y) {
    int i = blockIdx.x * blockDim.x + threadIdx.x;   // 8192*512/8 groups
    int row = i >> 6;
    int col8 = (i & 63) * 8;
    int h = col8 >> 6;
    float l = Lp[h * 8192 + row] + Lp[65536 + h * 8192 + row]
            + Lp[131072 + h * 8192 + row] + Lp[196608 + h * 8192 + row];
    float inv = 1.0f / l;
    size_t off = (size_t)row * 512 + col8;
    bf16x8 a = *reinterpret_cast<const bf16x8*>(Op01 + off);
    bf16x8 c = *reinterpret_cast<const bf16x8*>(Op01 + 4194304 + off);
    bf16x8 d = *reinterpret_cast<const bf16x8*>(Op23 + off);
    bf16x8 e = *reinterpret_cast<const bf16x8*>(Op23 + 4194304 + off);
    bf16x8 o;
#pragma unroll
    for (int j = 0; j < 8; ++j)
        o[j] = (bf16)((((float)a[j] + (float)c[j]) + ((float)d[j] + (float)e[j])) * inv);
    *reinterpret_cast<bf16x8*>(Y + off) = o;
}

extern "C" void kernel_launch(void* const* d_in, const int* in_sizes, int n_in,
                              void* d_out, int out_size, void* d_ws, size_t ws_size,
                              hipStream_t stream) {
    const float* x   = (const float*)d_in[0];
    const float* q   = (const float*)d_in[1];
    const float* Wkv = (const float*)d_in[2];
    const float* Wp  = (const float*)d_in[3];
    float* out = (float*)d_out;

    char* ws = (char*)d_ws;
    bf16*  Kb   = (bf16*)(ws);                 //  0 .. 8 MB
    bf16*  Vt   = (bf16*)(ws + 8388608);       //  8 .. 16 MB
    bf16*  Op01 = (bf16*)(ws + 16777216);      // 16 .. 32 MB  [2][8192][512]
    bf16*  Yb   = (bf16*)(ws + 33554432);      // 32 .. 40 MB
    bf16*  Wkvt = (bf16*)(ws + 41943040);      // 40 .. 41 MB
    bf16*  Wpt  = (bf16*)(ws + 42991616);      // +0.5 MB
    float* Lp   = (float*)(ws + 43515904);     // +1 MB [4][8][8192]
    bf16*  Op23 = (bf16*)d_out;                // parts 2,3 staged in d_out (16 MB),
                                               // consumed by combine, then overwritten by proj

    transpose_cast_kernel<<<(512 * 1024) / 256, 256, 0, stream>>>(Wkv, Wkvt, 512, 1024);
    transpose_cast_kernel<<<(512 * 512) / 256, 256, 0, stream>>>(Wp, Wpt, 512, 512);
    gemm_kv_kernel<<<dim3(64, 8), 256, 0, stream>>>(x, Wkvt, Kb, Vt);
    attn_kernel<<<1024, 512, 0, stream>>>(q, Kb, Vt, Op01, Op23, Lp);
    combine_kernel<<<(8192 * 512 / 8) / 256, 256, 0, stream>>>(Op01, Op23, Lp, Yb);
    gemm_proj_kernel<<<dim3(64, 4), 256, 0, stream>>>(Yb, Wpt, out);
}

// Round 23
// 126.157 us; speedup vs baseline: 1.0614x; 1.0614x over previous
//
#include <hip/hip_runtime.h>

typedef __bf16 bf16;
typedef bf16 bf16x8 __attribute__((ext_vector_type(8)));
typedef bf16 bf16x4 __attribute__((ext_vector_type(4)));
typedef float f32x4 __attribute__((ext_vector_type(4)));
typedef float f32x16 __attribute__((ext_vector_type(16)));
typedef unsigned int u32;

#define DEV_INLINE __device__ __forceinline__

DEV_INLINE f32x4 mfma16(bf16x8 a, bf16x8 b, f32x4 c) {
    return __builtin_amdgcn_mfma_f32_16x16x32_bf16(a, b, c, 0, 0, 0);
}
DEV_INLINE f32x16 mfma32(bf16x8 a, bf16x8 b, f32x16 c) {
    return __builtin_amdgcn_mfma_f32_32x32x16_bf16(a, b, c, 0, 0, 0);
}

#define GLD16(gp, lp) __builtin_amdgcn_global_load_lds( \
    (const __attribute__((address_space(1))) void*)(gp), \
    (__attribute__((address_space(3))) void*)(lp), 16, 0, 0)

// ---------------- transpose cast: in f32 [K][N] -> out bf16 [N][K] ----------------
__global__ void transpose_cast_kernel(const float* __restrict__ in, bf16* __restrict__ out,
                                      int K, int N) {
    int idx = blockIdx.x * blockDim.x + threadIdx.x;
    if (idx < K * N) {
        int n = idx / K, k = idx - n * K;
        out[idx] = (bf16)in[k * N + n];
    }
}

// ---------------- kv GEMM: x f32 [8192x512] x W_kv^T -> K bf16 natural, V bf16 head-transposed
// A staged directly from f32 (cast fused). V t-index PERMUTED (swap bits 2,3
// within each 16-run) so the attention PV A-fragment is one contiguous 16B chunk.
__launch_bounds__(256, 2)
__global__ void gemm_kv_kernel(const float* __restrict__ A,  // x f32 [8192][512]
                               const bf16* __restrict__ Bt,  // W_kv^T bf16 [1024][512]
                               bf16* __restrict__ Kout,      // [8][1024][512]
                               bf16* __restrict__ Vt)        // [8][8][64][1024] (t-permuted)
{
    __shared__ bf16 As[128][32];
    __shared__ bf16 Bs[128][32];
    const int bm = blockIdx.x, bn = blockIdx.y;
    const int tid = threadIdx.x;
    const int lane = tid & 63, w = tid >> 6;
    const int wm = (w >> 1) * 64, wn = (w & 1) * 64;
    const int lr = lane & 15, kg = lane >> 4;

    const f32x4 fz = {0.f, 0.f, 0.f, 0.f};
    f32x4 acc[4][4];
    for (int i = 0; i < 4; ++i)
        for (int j = 0; j < 4; ++j) acc[i][j] = fz;

    const int srow = tid >> 2, sc4 = tid & 3;

    for (int k0 = 0; k0 < 512; k0 += 32) {
        __syncthreads();
        for (int rr = 0; rr < 2; ++rr) {
            int row = srow + rr * 64;
            const float* ap = A + (size_t)(bm * 128 + row) * 512 + k0 + (sc4 << 3);
            f32x4 a0 = *reinterpret_cast<const f32x4*>(ap);
            f32x4 a1 = *reinterpret_cast<const f32x4*>(ap + 4);
            bf16x8 av;
            for (int j = 0; j < 4; ++j) { av[j] = (bf16)a0[j]; av[4 + j] = (bf16)a1[j]; }
            *reinterpret_cast<bf16x8*>(&As[row][(sc4 ^ (row & 3)) << 3]) = av;
            *reinterpret_cast<bf16x8*>(&Bs[row][(sc4 ^ (row & 3)) << 3]) =
                *reinterpret_cast<const bf16x8*>(Bt + (size_t)(bn * 128 + row) * 512 + k0 + (sc4 << 3));
        }
        __syncthreads();
        bf16x8 af[4], bfr[4];
        for (int mi = 0; mi < 4; ++mi) {
            int row = wm + mi * 16 + lr;
            af[mi] = *reinterpret_cast<const bf16x8*>(&As[row][(kg ^ (row & 3)) << 3]);
        }
        for (int ni = 0; ni < 4; ++ni) {
            int row = wn + ni * 16 + lr;
            bfr[ni] = *reinterpret_cast<const bf16x8*>(&Bs[row][(kg ^ (row & 3)) << 3]);
        }
        for (int mi = 0; mi < 4; ++mi)
            for (int ni = 0; ni < 4; ++ni)
                acc[mi][ni] = mfma16(af[mi], bfr[ni], acc[mi][ni]);
    }

    for (int mi = 0; mi < 4; ++mi) {
        int mbase = bm * 128 + wm + mi * 16 + kg * 4;  // C/D: row=(lane>>4)*4+reg
        for (int ni = 0; ni < 4; ++ni) {
            int col = bn * 128 + wn + ni * 16 + lr;    // C/D: col=lane&15
            if (col < 512) {
                for (int r = 0; r < 4; ++r)
                    Kout[(size_t)(mbase + r) * 512 + col] = (bf16)acc[mi][ni][r];
            } else {
                int c = col - 512, h = c >> 6, d = c & 63;
                int b = mbase >> 10, t = mbase & 1023;  // 4 rows share batch (4-aligned)
                int tp = (t & ~12) | ((t & 4) << 1) | ((t & 8) >> 1);  // swap bits 2,3
                bf16x4 pk;
                for (int r = 0; r < 4; ++r) pk[r] = (bf16)acc[mi][ni][r];
                *reinterpret_cast<bf16x4*>(Vt + (size_t)((b * 8 + h) * 64 + d) * 1024 + tp) = pk;
            }
        }
    }
}

// ---------------- proj GEMM with FUSED partial-combine ----------------
// A = (Op0 + Op1) / (l0 + l1), normalized during LDS staging (r16-proven).
__launch_bounds__(256, 2)
__global__ void gemm_proj_kernel(const bf16* __restrict__ Op,  // [2][8192][512] partial O
                                 const float* __restrict__ Lp, // [2][8][8192] partial l
                                 const bf16* __restrict__ Bt,  // W_proj^T bf16 [512][512]
                                 float* __restrict__ out)      // [8192][512]
{
    __shared__ bf16 As[128][32];
    __shared__ bf16 Bs[128][32];
    const int bm = blockIdx.x, bn = blockIdx.y;
    const int tid = threadIdx.x;
    const int lane = tid & 63, w = tid >> 6;
    const int wm = (w >> 1) * 64, wn = (w & 1) * 64;
    const int lr = lane & 15, kg = lane >> 4;

    const f32x4 fz = {0.f, 0.f, 0.f, 0.f};
    f32x4 acc[4][4];
    for (int i = 0; i < 4; ++i)
        for (int j = 0; j < 4; ++j) acc[i][j] = fz;

    const int srow = tid >> 2, sc4 = tid & 3;

    for (int k0 = 0; k0 < 512; k0 += 32) {
        __syncthreads();
        for (int rr = 0; rr < 2; ++rr) {
            int row = srow + rr * 64;
            int grow = bm * 128 + row;
            int kc = k0 + (sc4 << 3);
            int hh = kc >> 6;
            float l = Lp[hh * 8192 + grow] + Lp[65536 + hh * 8192 + grow];
            float inv = 1.0f / l;
            size_t off = (size_t)grow * 512 + kc;
            bf16x8 a = *reinterpret_cast<const bf16x8*>(Op + off);
            bf16x8 c = *reinterpret_cast<const bf16x8*>(Op + 4194304 + off);
            bf16x8 av;
            for (int j = 0; j < 8; ++j)
                av[j] = (bf16)(((float)a[j] + (float)c[j]) * inv);
            *reinterpret_cast<bf16x8*>(&As[row][(sc4 ^ (row & 3)) << 3]) = av;
            *reinterpret_cast<bf16x8*>(&Bs[row][(sc4 ^ (row & 3)) << 3]) =
                *reinterpret_cast<const bf16x8*>(Bt + (size_t)(bn * 128 + row) * 512 + k0 + (sc4 << 3));
        }
        __syncthreads();
        bf16x8 af[4], bfr[4];
        for (int mi = 0; mi < 4; ++mi) {
            int row = wm + mi * 16 + lr;
            af[mi] = *reinterpret_cast<const bf16x8*>(&As[row][(kg ^ (row & 3)) << 3]);
        }
        for (int ni = 0; ni < 4; ++ni) {
            int row = wn + ni * 16 + lr;
            bfr[ni] = *reinterpret_cast<const bf16x8*>(&Bs[row][(kg ^ (row & 3)) << 3]);
        }
        for (int mi = 0; mi < 4; ++mi)
            for (int ni = 0; ni < 4; ++ni)
                acc[mi][ni] = mfma16(af[mi], bfr[ni], acc[mi][ni]);
    }

    for (int mi = 0; mi < 4; ++mi) {
        int mbase = bm * 128 + wm + mi * 16 + kg * 4;
        for (int ni = 0; ni < 4; ++ni) {
            int col = bn * 128 + wn + ni * 16 + lr;
            for (int r = 0; r < 4; ++r)
                out[(size_t)(mbase + r) * 512 + col] = acc[mi][ni][r];
        }
    }
}

// ---------------- flash attention: r19 structure, 128-elem-row LDS (16-wide XOR) ----------------
// 2-way S-split, 64-s tiles, 512 blocks x 8 waves. K and V tiles packed as
// [32 LDS-rows x 128 elems] (two logical 64-elem rows per LDS row); physical
// chunk pc = cc ^ (r&15), cc = (s&1)*8|c, r = s>>1 -- conflict-free (r21: 0).
__launch_bounds__(512, 2)
__global__ void attn_kernel(const float* __restrict__ Qr,  // q f32 [8][1024][512]
                            const bf16* __restrict__ Kb,   // [8][1024][512]
                            const bf16* __restrict__ Vt,   // [8][8][64][1024] t-permuted
                            bf16* __restrict__ Op,         // [2][8192][512] partial O^T (bf16)
                            float* __restrict__ Lp)        // [2][8][8192] partial l
{
    __shared__ bf16 sK[2][32][128];
    __shared__ bf16 sV[2][32][128];

    const int raw = blockIdx.x;
    const int h = raw & 7;              // head on low bits -> per-XCD K/V locality
    const int shalf = (raw >> 3) & 1;   // S-half
    const int qseg = (raw >> 4) & 3;
    const int b = raw >> 6;
    const int tid = threadIdx.x, lane = tid & 63, w = tid >> 6;   // w in 0..7
    const int lq = lane & 31, hi = lane >> 5;
    const int qrow = b * 1024 + qseg * 256 + w * 32 + lq;
    const int sbase = shalf * 2304;     // 36 tiles of 64 s

    // Q B-fragments from f32 with fused scale (1/8 * log2e): col=q=lane&31
    const float QSC = 0.18033688011112306f;
    bf16x8 qf[4];
#pragma unroll
    for (int ds = 0; ds < 4; ++ds) {
        const float* qp = Qr + (size_t)qrow * 512 + h * 64 + ds * 16 + hi * 8;
        f32x4 q0 = *reinterpret_cast<const f32x4*>(qp);
        f32x4 q1 = *reinterpret_cast<const f32x4*>(qp + 4);
#pragma unroll
        for (int j = 0; j < 4; ++j) {
            qf[ds][j]     = (bf16)(q0[j] * QSC);
            qf[ds][4 + j] = (bf16)(q1[j] * QSC);
        }
    }

    const f32x16 Z16 = {0,0,0,0,0,0,0,0,0,0,0,0,0,0,0,0};
    f32x16 O0 = Z16, O1 = Z16, lv = Z16;

    // ---- read offsets: logical (row=lq, chunk c) -> packed layout ----
    const bf16* Kf = &sK[0][0][0];
    const bf16* Vf = &sV[0][0][0];
    int koffE[4];
#pragma unroll
    for (int ds = 0; ds < 4; ++ds) {
        int c = ds * 2 + hi;
        int r = lq >> 1;
        int cc = ((lq & 1) << 3) | c;
        koffE[ds] = r * 128 + ((cc ^ r) << 3);
    }

    // ---- staging geometry (packed [32][128], 16-wide XOR) ----
    const int rl = w * 4 + (lane >> 4);
    const int ccs = (lane & 15) ^ (rl & 15);
    const int srow2 = w * 8 + 2 * (lane >> 4) + (ccs >> 3);   // logical source row in tile
    const size_t koff = (size_t)srow2 * 512 + (ccs & 7) * 8;
    const size_t voff = (size_t)srow2 * 1024 + (ccs & 7) * 8;

    auto kv_base = [&](int t, const bf16*& kp, const bf16*& vp) {
        int gs = sbase + t * 64;         // global s offset, 0..4544
        int jj = gs >> 9, tin = gs & 511;
        if (jj < 7) {
            int m7 = 7 * b + jj;
            int src_b = ((m7 & 7) - (m7 >> 3)) & 7;
            kp = Kb + (size_t)(src_b * 1024 + tin) * 512 + h * 64;
            vp = Vt + (size_t)((src_b * 8 + h) * 64) * 1024 + tin;
        } else {
            int tpos = (jj - 7) * 512 + tin;
            kp = Kb + (size_t)(b * 1024 + tpos) * 512 + h * 64;
            vp = Vt + (size_t)((b * 8 + h) * 64) * 1024 + tpos;
        }
    };

    auto stage = [&](int buf, int t) {
        const bf16 *kp, *vp;
        kv_base(t, kp, vp);
        GLD16(kp + koff, &sK[buf][w * 4][0]);
        GLD16(vp + voff, &sV[buf][w * 4][0]);
    };

    // compute one 64-s tile (cb must be a literal at the call site)
    auto computeTile = [&](int cb) {
        const int kb = cb * 4096;
        f32x16 s0, s1;
        __builtin_amdgcn_s_setprio(1);
        {   // first k-slice consumes the persistent zero C (no 32x mov init)
            bf16x8 k0 = *reinterpret_cast<const bf16x8*>(Kf + kb + koffE[0]);
            bf16x8 k1 = *reinterpret_cast<const bf16x8*>(Kf + kb + 2048 + koffE[0]);
            s0 = mfma32(k0, qf[0], Z16);
            s1 = mfma32(k1, qf[0], Z16);
        }
#pragma unroll
        for (int ds = 1; ds < 4; ++ds) {
            bf16x8 k0 = *reinterpret_cast<const bf16x8*>(Kf + kb + koffE[ds]);
            bf16x8 k1 = *reinterpret_cast<const bf16x8*>(Kf + kb + 2048 + koffE[ds]);
            s0 = mfma32(k0, qf[ds], s0);
            s1 = mfma32(k1, qf[ds], s1);
        }
        __builtin_amdgcn_s_setprio(0);

        // softmax numerator: p = 2^s, raw v_exp_f32 (scale cancels in O/l)
#pragma unroll
        for (int i = 0; i < 16; ++i) {
            float p0 = __builtin_amdgcn_exp2f(s0[i]); s0[i] = p0;
            float p1 = __builtin_amdgcn_exp2f(s1[i]); s1[i] = p1;
            lv[i] += p0 + p1;
        }

        __builtin_amdgcn_s_setprio(1);
#pragma unroll
        for (int ssub = 0; ssub < 4; ++ssub) {
            bf16x8 pf;
#pragma unroll
            for (int i = 0; i < 8; ++i) {
                float pv = (ssub < 2) ? ((ssub & 1) ? s0[8 + i] : s0[i])
                                      : ((ssub & 1) ? s1[8 + i] : s1[i]);
                pf[i] = (bf16)pv;
            }
            bf16x8 a0 = *reinterpret_cast<const bf16x8*>(Vf + kb + koffE[ssub]);
            bf16x8 a1 = *reinterpret_cast<const bf16x8*>(Vf + kb + 2048 + koffE[ssub]);
            O0 = mfma32(a0, pf, O0);
            O1 = mfma32(a1, pf, O1);
        }
        __builtin_amdgcn_s_setprio(0);
    };

    stage(0, 0);   // prologue

    // 36 tiles of 64 s: each iteration computes tiles t (buf0) and t+1 (buf1)
    for (int t = 0; t < 36; t += 2) {
        __syncthreads();                    // drains vmcnt (stage writes) + barrier
        stage(1, t + 1);
        computeTile(0);
        __syncthreads();
        if (t + 2 < 36) stage(0, t + 2);
        computeTile(1);
    }

    // ---- epilogue: reduce partial l, store partial O^T (UNnormalized, bf16) + l ----
    float lrun = 0.f;
#pragma unroll
    for (int i = 0; i < 16; ++i) lrun += lv[i];
    lrun += __shfl_xor(lrun, 32);
    if (hi == 0) Lp[shalf * 65536 + h * 8192 + qrow] = lrun;

    bf16* Od = Op + (size_t)shalf * 4194304;
#pragma unroll
    for (int dh = 0; dh < 2; ++dh) {
#pragma unroll
        for (int q4 = 0; q4 < 4; ++q4) {
            bf16x4 pk;
#pragma unroll
            for (int i = 0; i < 4; ++i)
                pk[i] = (bf16)(dh ? O1[q4 * 4 + i] : O0[q4 * 4 + i]);
            *reinterpret_cast<bf16x4*>(
                Od + (size_t)qrow * 512 + h * 64 + dh * 32 + q4 * 8 + hi * 4) = pk;
        }
    }
}

extern "C" void kernel_launch(void* const* d_in, const int* in_sizes, int n_in,
                              void* d_out, int out_size, void* d_ws, size_t ws_size,
                              hipStream_t stream) {
    const float* x   = (const float*)d_in[0];
    const float* q   = (const float*)d_in[1];
    const float* Wkv = (const float*)d_in[2];
    const float* Wp  = (const float*)d_in[3];
    float* out = (float*)d_out;

    char* ws = (char*)d_ws;
    bf16*  Kb   = (bf16*)(ws);                 //  0 .. 8 MB
    bf16*  Vt   = (bf16*)(ws + 8388608);       //  8 .. 16 MB
    bf16*  Opar = (bf16*)(ws + 16777216);      // 16 .. 32 MB  [2][8192][512]
    bf16*  Wkvt = (bf16*)(ws + 41943040);      // 40 .. 41 MB
    bf16*  Wpt  = (bf16*)(ws + 42991616);      // +0.5 MB
    float* Lp   = (float*)(ws + 43515904);     // +0.5 MB [2][8][8192]

    transpose_cast_kernel<<<(512 * 1024) / 256, 256, 0, stream>>>(Wkv, Wkvt, 512, 1024);
    transpose_cast_kernel<<<(512 * 512) / 256, 256, 0, stream>>>(Wp, Wpt, 512, 512);
    gemm_kv_kernel<<<dim3(64, 8), 256, 0, stream>>>(x, Wkvt, Kb, Vt);
    attn_kernel<<<512, 512, 0, stream>>>(q, Kb, Vt, Opar, Lp);
    gemm_proj_kernel<<<dim3(64, 4), 256, 0, stream>>>(Opar, Lp, Wpt, out);
}